// Round 6
// baseline (2056.289 us; speedup 1.0000x reference)
//
#include <hip/hip_runtime.h>
#include <cmath>

// Problem dims (fixed by setup_inputs)
#define T_    4
#define B_    64
#define N_    196
#define P_    768
#define D_    256
#define BN_   (B_*N_)          // 12544
#define M_    (T_*BN_)         // 50176
#define SITES (BN_*D_)         // 3211264

#define TILE  64
#define TK    16
#define MBLKS (M_/TILE)        // 784
#define NBLKS (D_/TILE)        // 4

// ---------------------------------------------------------------------------
// Kernel 1: numpy c_einsum f32 emulation.
// Per output element: 4 SSE lanes; lane j = sequential f32 sum over p≡j mod 4
// of fl32(x*w) (separate mul/add roundings, no FMA). Final combine
// (l0+l1)+(l2+l3). h written into d_out scratch, layout [m][d].
// ---------------------------------------------------------------------------
extern "C" __global__ __launch_bounds__(256)
void gemm_f32emu(const float* __restrict__ x, const float* __restrict__ w,
                 float* __restrict__ h) {
    __shared__ __align__(16) float As[TK][72];
    __shared__ __align__(16) float Bs[TK][72];

    const int tid  = threadIdx.x;
    const int tx   = tid & 15;       // d-group
    const int ty   = tid >> 4;       // m-group
    const int m0   = blockIdx.x * TILE;
    const int d0   = blockIdx.y * TILE;
    const int lrow = tid >> 2;
    const int lk   = (tid & 3) * 4;

    float acc[4][4][4];              // [i][j][sse_lane]
#pragma unroll
    for (int i = 0; i < 4; ++i)
#pragma unroll
        for (int j = 0; j < 4; ++j)
#pragma unroll
            for (int l = 0; l < 4; ++l) acc[i][j][l] = 0.0f;

    for (int k0 = 0; k0 < P_; k0 += TK) {
        const float4 av = *(const float4*)(x + (size_t)(m0 + lrow) * P_ + k0 + lk);
        const float4 bv = *(const float4*)(w + (size_t)(d0 + lrow) * P_ + k0 + lk);
        As[lk + 0][lrow] = av.x; As[lk + 1][lrow] = av.y;
        As[lk + 2][lrow] = av.z; As[lk + 3][lrow] = av.w;
        Bs[lk + 0][lrow] = bv.x; Bs[lk + 1][lrow] = bv.y;
        Bs[lk + 2][lrow] = bv.z; Bs[lk + 3][lrow] = bv.w;
        __syncthreads();
#pragma unroll
        for (int kk = 0; kk < TK; ++kk) {
            const int lane = kk & 3;           // p = k0+kk, k0%16==0
            float af[4], bf[4];
#pragma unroll
            for (int i = 0; i < 4; ++i) af[i] = As[kk][ty * 4 + i];
#pragma unroll
            for (int j = 0; j < 4; ++j) bf[j] = Bs[kk][tx * 4 + j];
#pragma unroll
            for (int i = 0; i < 4; ++i)
#pragma unroll
                for (int j = 0; j < 4; ++j)
                    acc[i][j][lane] =
                        __fadd_rn(acc[i][j][lane], __fmul_rn(af[i], bf[j]));
        }
        __syncthreads();
    }

#pragma unroll
    for (int i = 0; i < 4; ++i) {
        float4 o;
        float* hv = &o.x;
#pragma unroll
        for (int j = 0; j < 4; ++j) {
            const float l01 = __fadd_rn(acc[i][j][0], acc[i][j][1]);
            const float l23 = __fadd_rn(acc[i][j][2], acc[i][j][3]);
            hv[j] = __fadd_rn(l01, l23);
        }
        *(float4*)(h + (size_t)(m0 + ty * 4 + i) * D_ + d0 + tx * 4) = o;
    }
}

// ---------------------------------------------------------------------------
// Kernel 2: mean — numpy reduce on the transposed VIEW: per channel d,
// fully SEQUENTIAL f32 accumulation over m=0..M-1, then f32 divide.
// 16 blocks x 64 threads; lanes 0..15 active (d = blk*16+lane).
// ---------------------------------------------------------------------------
extern "C" __global__ __launch_bounds__(64)
void mean_seq(const float* __restrict__ h, float* __restrict__ mean_) {
    const int lane = threadIdx.x;
    if (lane >= 16) return;
    const int d = blockIdx.x * 16 + lane;
    float acc = 0.0f;
    for (int m = 0; m < M_; ++m)
        acc = __fadd_rn(acc, h[(size_t)m * D_ + d]);
    mean_[d] = __fdiv_rn(acc, 50176.0f);
}

// ---------------------------------------------------------------------------
// Kernel 3: var — ((h-mean)**2) is a fresh CONTIGUOUS array; its mean is
// per (t,b): acc = fl32(acc + pairwise_f32(chunk of 196)). Chunk interior
// emulated in f64 (pairwise ~ f64), join rounding in f32 emulated exactly.
// inv = 1/sqrt(var+1e-5), all correctly-rounded f32 ops.
// One block (64 lanes) per channel d.
// ---------------------------------------------------------------------------
extern "C" __global__ __launch_bounds__(64)
void var_seq(const float* __restrict__ h, const float* __restrict__ mean_,
             float* __restrict__ inv_) {
    const int d    = blockIdx.x;
    const int lane = threadIdx.x;
    const float mn = mean_[d];
    float accf = 0.0f;
    for (int tb = 0; tb < T_ * B_; ++tb) {
        double part = 0.0;
        for (int n = lane; n < N_; n += 64) {
            const float hv = h[((size_t)tb * N_ + n) * D_ + d];
            const float t1 = __fsub_rn(hv, mn);
            const float sq = __fmul_rn(t1, t1);
            part += (double)sq;
        }
#pragma unroll
        for (int off = 32; off; off >>= 1) part += __shfl_down(part, off);
        const float chunk = (float)part;          // lane 0 holds true value
        accf = __fadd_rn(accf, chunk);
    }
    if (lane == 0) {
        const float var = __fdiv_rn(accf, 50176.0f);
        inv_[d] = __fdiv_rn(1.0f, __fsqrt_rn(__fadd_rn(var, 1e-5f)));
    }
}

// ---------------------------------------------------------------------------
// Kernel 4: BN-apply + LIF1 + tAPE + LIF2, exact numpy-f32 op order.
// pe: NEP-50 — np.log(10000.0) is a strong f64 scalar, so div/arg are f64;
// sin/cos in f64, rounded to f32 on assignment. Spike ties: >= (H(0)=1).
// In-place on d_out: each thread reads its own 4 h cells, then overwrites.
// ---------------------------------------------------------------------------
extern "C" __global__ __launch_bounds__(256)
void lif_final(float* __restrict__ out, const float* __restrict__ mean_,
               const float* __restrict__ inv_, const float* __restrict__ gamma,
               const float* __restrict__ beta) {
    const int idx = blockIdx.x * 256 + threadIdx.x;   // (bn, d)
    const int d = idx & (D_ - 1);
    const int n = (idx >> 8) % N_;

    const float mn = mean_[d];
    const float iv = inv_[d];
    const float g  = gamma[d];
    const float b  = beta[d];

    const double dv  = exp((double)(d & ~1) * (-9.210340371976184 / 256.0));
    const double arg = ((double)n * dv) * (256.0 / 196.0);
    const float  pe  = (d & 1) ? (float)cos(arg) : (float)sin(arg);

    float hv[4];
#pragma unroll
    for (int t = 0; t < T_; ++t) hv[t] = out[(size_t)t * SITES + idx];

    float v1 = 0.0f, v2 = 0.0f, s2v[4];
#pragma unroll
    for (int t = 0; t < T_; ++t) {
        const float t1 = __fsub_rn(hv[t], mn);
        const float u  = __fmul_rn(t1, iv);
        const float hb = __fadd_rn(__fmul_rn(u, g), b);
        v1 = __fadd_rn(v1, __fmul_rn(__fsub_rn(hb, v1), 0.5f));
        const float s1 = (v1 >= 0.5f) ? 1.0f : 0.0f;
        v1 = __fmul_rn(v1, __fsub_rn(1.0f, s1));
        const float y = __fadd_rn(s1, pe);
        v2 = __fadd_rn(v2, __fmul_rn(__fsub_rn(y, v2), 0.5f));
        const float s2 = (v2 >= 0.5f) ? 1.0f : 0.0f;
        v2 = __fmul_rn(v2, __fsub_rn(1.0f, s2));
        s2v[t] = s2;
    }
#pragma unroll
    for (int t = 0; t < T_; ++t) out[(size_t)t * SITES + idx] = s2v[t];
}

extern "C" void kernel_launch(void* const* d_in, const int* in_sizes, int n_in,
                              void* d_out, int out_size, void* d_ws, size_t ws_size,
                              hipStream_t stream) {
    const float* x     = (const float*)d_in[0];
    const float* w     = (const float*)d_in[1];
    const float* gamma = (const float*)d_in[2];
    const float* beta  = (const float*)d_in[3];
    float* out = (float*)d_out;

    float* mean_ = (float*)d_ws;         // 256 floats
    float* inv_  = mean_ + D_;           // 256 floats

    gemm_f32emu<<<dim3(MBLKS, NBLKS), 256, 0, stream>>>(x, w, out);
    mean_seq<<<16, 64, 0, stream>>>(out, mean_);
    var_seq<<<D_, 64, 0, stream>>>(out, mean_, inv_);
    lif_final<<<SITES / 256, 256, 0, stream>>>(out, mean_, inv_, gamma, beta);
}